// Round 4
// baseline (427.769 us; speedup 1.0000x reference)
//
#include <hip/hip_runtime.h>
#include <hip/hip_bf16.h>
#include <math.h>

#define N_  8
#define C_  528
#define T_  16
#define H_  32
#define W_  32
#define HW_ 1024
#define R_  1024
#define OUT_ 8
#define SCALE_ (1.0f/16.0f)
#define NYMAX_ 9   // max bilinear row-support (box extent <= 7 px -> <= 9 rows)

// ---------------------------------------------------------------------------
// Kernel 1: feat_t[n][p][c] = mean_t x[n][c][t][p], NCHW -> N(HW)C transpose.
// ---------------------------------------------------------------------------
__global__ __launch_bounds__(256) void mean_transpose(
    const float* __restrict__ x, float* __restrict__ feat_t) {
  const int p0 = blockIdx.x * 64;
  const int c0 = blockIdx.y * 64;
  const int n  = blockIdx.z;

  __shared__ float tile[64][68];

  const int tid = threadIdx.x;
  const int p4  = (tid & 15) * 4;
  const int clo = tid >> 4;

  const float inv_t = 1.0f / 16.0f;
  #pragma unroll
  for (int k = 0; k < 4; ++k) {
    const int c_local = clo + 16 * k;
    const int c = c0 + c_local;
    float4 acc = make_float4(0.f, 0.f, 0.f, 0.f);
    if (c < C_) {
      const float* src = x + ((size_t)(n * C_ + c) * T_) * HW_ + p0 + p4;
      #pragma unroll
      for (int t = 0; t < T_; ++t) {
        const float4 v = *(const float4*)(src + t * HW_);
        acc.x += v.x; acc.y += v.y; acc.z += v.z; acc.w += v.w;
      }
    }
    tile[p4 + 0][c_local] = acc.x * inv_t;
    tile[p4 + 1][c_local] = acc.y * inv_t;
    tile[p4 + 2][c_local] = acc.z * inv_t;
    tile[p4 + 3][c_local] = acc.w * inv_t;
  }
  __syncthreads();

  const int c4 = (tid & 15) * 4;
  const int p  = tid >> 4;
  if (c0 + c4 < C_) {
    #pragma unroll
    for (int k = 0; k < 4; ++k) {
      const int p_out = p + 16 * k;
      const float4 v = *(const float4*)&tile[p_out][c4];
      *(float4*)&feat_t[((size_t)n * HW_ + p0 + p_out) * C_ + c0 + c4] = v;
    }
  }
}

// ---------------------------------------------------------------------------
// Kernel 2: one block per (roi, y-row). Fixed 9-tap zero-padded X gather,
// row partial -> partials[r][yk][C_]. Rows outside support write zeros
// (covers the 0xAA ws poison deterministically, no atomics).
// grid = (1024, 9), block = 128.
// ---------------------------------------------------------------------------
__global__ __launch_bounds__(128) void roi_rows(
    const float* __restrict__ feat_t, const float* __restrict__ bbox,
    float* __restrict__ partials) {
  const int r   = blockIdx.x;
  const int yk  = blockIdx.y;
  const int tid = threadIdx.x;

  __shared__ float sA[80];   // sAy = sA[0..39], sAx = sA[40..79], zero-padded
  __shared__ int   sb[3];    // ylo, xlo, bidx

  if (tid < 80) sA[tid] = 0.f;
  __syncthreads();

  if (tid < 32) {
    const bool is_y = (tid < 16);
    const int  i    = tid & 15;
    const float s1  = bbox[r * 5 + (is_y ? 2 : 1)] * SCALE_ - 0.5f;
    const float s2  = bbox[r * 5 + (is_y ? 4 : 3)] * SCALE_ - 0.5f;
    const float bin = (s2 - s1) * (1.0f / OUT_);
    const float v   = s1 + ((float)i + 0.5f) * (bin * 0.5f);
    const bool valid = (v >= -1.0f) && (v <= (float)H_);
    int lo = 64;
    if (valid) {
      float vc  = fminf(fmaxf(v, 0.0f), 31.0f);
      float lof = floorf(vc);
      float fr  = vc - lof;
      lo = (int)lof;
      int hi = min(lo + 1, 31);
      float* A = is_y ? sA : (sA + 40);
      atomicAdd(&A[lo], 1.0f - fr);
      atomicAdd(&A[hi], fr);
    }
    int mn = lo;
    #pragma unroll
    for (int m = 8; m >= 1; m >>= 1) mn = min(mn, __shfl_xor(mn, m, 16));
    mn = min(mn, 31);   // guard (support always non-empty here, but safe)
    if (tid == 0)  { sb[0] = mn; sb[2] = (int)bbox[r * 5]; }
    if (tid == 16) { sb[1] = mn; }
  }
  __syncthreads();

  const int ylo  = sb[0];
  const int xlo  = sb[1];
  const int bidx = sb[2];
  const int row  = ylo + yk;          // <= 39
  const float wy = sA[row];           // zero-padded beyond support

  float4* dst = (float4*)(partials + ((size_t)r * NYMAX_ + yk) * C_);

  for (int q = tid; q < 132; q += 128) {
    float4 rs = make_float4(0.f, 0.f, 0.f, 0.f);
    if (wy != 0.f) {
      const float* rp =
          feat_t + ((size_t)bidx * HW_ + row * W_ + xlo) * C_ + q * 4;
      #pragma unroll
      for (int k = 0; k < 9; ++k) {
        const float wx = sA[40 + xlo + k];   // zero beyond support
        const float4 v = *(const float4*)(rp + (size_t)k * C_);
        rs.x += wx * v.x; rs.y += wx * v.y;
        rs.z += wx * v.z; rs.w += wx * v.w;
      }
      rs.x *= wy; rs.y *= wy; rs.z *= wy; rs.w *= wy;
    }
    dst[q] = rs;
  }
}

// ---------------------------------------------------------------------------
// Kernel 3: per-roi reduce 9 row-partials -> pooled, then 3-layer MLP.
// grid = 1024, block = 256.
// ---------------------------------------------------------------------------
__global__ __launch_bounds__(256) void mlp(
    const float* __restrict__ partials,
    const float* __restrict__ W1, const float* __restrict__ b1,
    const float* __restrict__ W2, const float* __restrict__ b2,
    const float* __restrict__ W3, const float* __restrict__ b3,
    float* __restrict__ out) {
  const int r = blockIdx.x;
  const int tid = threadIdx.x;

  __shared__ __align__(16) float pooled[C_];
  __shared__ float h1p[2][128];
  __shared__ float h1[128];
  __shared__ float p2[8][32];
  __shared__ float h2[32];

  if (tid < 132) {
    const float4* src = (const float4*)(partials + (size_t)r * NYMAX_ * C_);
    float4 a = make_float4(0.f, 0.f, 0.f, 0.f);
    #pragma unroll
    for (int yk = 0; yk < NYMAX_; ++yk) {
      const float4 v = src[yk * 132 + tid];
      a.x += v.x; a.y += v.y; a.z += v.z; a.w += v.w;
    }
    const float s = 1.0f / 256.0f;
    a.x *= s; a.y *= s; a.z *= s; a.w *= s;
    *(float4*)&pooled[tid * 4] = a;
  }
  __syncthreads();

  // --- Layer 1 (528 -> 128, relu): 2 half-K partials x 128 outputs --------
  {
    const int j = tid & 127;
    const int half = tid >> 7;
    const int cb = half * 264;
    float acc = 0.f;
    const float* w = W1 + j;
    #pragma unroll 4
    for (int c = cb; c < cb + 264; c += 4) {
      const float4 p = *(const float4*)&pooled[c];
      acc += p.x * w[(size_t)(c + 0) * 128];
      acc += p.y * w[(size_t)(c + 1) * 128];
      acc += p.z * w[(size_t)(c + 2) * 128];
      acc += p.w * w[(size_t)(c + 3) * 128];
    }
    h1p[half][j] = acc;
  }
  __syncthreads();
  if (tid < 128) h1[tid] = fmaxf(h1p[0][tid] + h1p[1][tid] + b1[tid], 0.f);
  __syncthreads();

  // --- Layer 2 (128 -> 32): 8 partials x 32 outputs -----------------------
  {
    const int j = tid & 31;
    const int part = tid >> 5;
    float acc = 0.f;
    #pragma unroll
    for (int k = part * 16; k < part * 16 + 16; ++k) {
      acc += h1[k] * W2[k * 32 + j];
    }
    p2[part][j] = acc;
  }
  __syncthreads();
  if (tid < 32) {
    float acc = b2[tid];
    #pragma unroll
    for (int p = 0; p < 8; ++p) acc += p2[p][tid];
    h2[tid] = acc;
  }
  __syncthreads();

  // --- Layer 3 (32 -> 1) + sigmoid, wave reduce ---------------------------
  if (tid < 64) {
    float t = (tid < 32) ? h2[tid] * W3[tid] : 0.f;
    #pragma unroll
    for (int off = 16; off >= 1; off >>= 1) t += __shfl_down(t, off);
    if (tid == 0) out[r] = 1.0f / (1.0f + expf(-(t + b3[0])));
  }
}

extern "C" void kernel_launch(void* const* d_in, const int* in_sizes, int n_in,
                              void* d_out, int out_size, void* d_ws, size_t ws_size,
                              hipStream_t stream) {
  const float* x    = (const float*)d_in[0];
  const float* bbox = (const float*)d_in[1];
  const float* W1   = (const float*)d_in[2];
  const float* b1   = (const float*)d_in[3];
  const float* W2   = (const float*)d_in[4];
  const float* b2   = (const float*)d_in[5];
  const float* W3   = (const float*)d_in[6];
  const float* b3   = (const float*)d_in[7];
  float* out = (float*)d_out;

  float* feat_t   = (float*)d_ws;                       // 17,301,504 B
  float* partials = (float*)((char*)d_ws + 17301504);   // 1024*9*528*4 = 19.5 MB

  mean_transpose<<<dim3(16, 9, 8), 256, 0, stream>>>(x, feat_t);
  roi_rows<<<dim3(R_, NYMAX_), 128, 0, stream>>>(feat_t, bbox, partials);
  mlp<<<R_, 256, 0, stream>>>(partials, W1, b1, W2, b2, W3, b3, out);
}